// Round 1
// baseline (3400.074 us; speedup 1.0000x reference)
//
#include <hip/hip_runtime.h>
#include <hip/hip_bf16.h>

typedef __attribute__((ext_vector_type(8))) short bf16x8;
typedef __attribute__((ext_vector_type(4))) float f32x4;

// sizes: T=512 B=64 K=256 H=512 G=4H=2048
// ws layout (bytes):
static constexpr size_t XG_OFF   = 0;                        // bf16 Xg [32768][2048]  134217728 B
static constexpr size_t WXT_OFF  = 134217728;                // bf16 frag-tiled W_x     1048576 B
static constexpr size_t WHT_OFF  = WXT_OFF + 1048576;        // bf16 frag-tiled W_h     2097152 B
static constexpr size_t HBUF_OFF = WHT_OFF + 2097152;        // bf16 h double-buffer     131072 B
static constexpr size_t BAR_OFF  = HBUF_OFF + 131072;        // 4 barrier counters          256 B

static __device__ __forceinline__ short f2bf(float f) {
    union { float f; unsigned u; } v; v.f = f;
    return (short)((v.u + 0x7fff + ((v.u >> 16) & 1)) >> 16);   // RNE
}
static __device__ __forceinline__ float bf2f(short s) {
    union { unsigned u; float f; } v;
    v.u = ((unsigned)(unsigned short)s) << 16; return v.f;
}
static __device__ __forceinline__ float sigm(float x)  { return 1.f / (1.f + __expf(-x)); }
static __device__ __forceinline__ float tanh_(float x) { return 1.f - 2.f / (1.f + __expf(2.f * x)); }

// ---------------- prep: convert+transpose W_x/W_h into MFMA B-fragment tiling, zero barrier ----
// tile layout: [kt][nt][16 col][32 k] bf16, so a wave's B-frag (lane l: B[(l>>4)*8+j][l&15])
// is one coalesced 16B read at tile_base + (l&15)*32 + (l>>4)*8  (shorts).
__global__ __launch_bounds__(256) void lstm_prep(const float* __restrict__ Wx,
                                                 const float* __restrict__ Wh,
                                                 short* __restrict__ WxT,
                                                 short* __restrict__ WhT,
                                                 int* __restrict__ bar) {
    int idx = blockIdx.x * 256 + threadIdx.x;
    if (idx < 524288) {                       // W_x [256][2048]
        int kg = idx >> 11, col = idx & 2047;
        int kt = kg >> 5, k = kg & 31, nt = col >> 4, c = col & 15;
        WxT[(size_t)((kt * 128 + nt) << 9) + c * 32 + k] = f2bf(Wx[idx]);
    } else if (idx < 524288 + 1048576) {      // W_h [512][2048] -> 16 slices of 128 cols
        int i2 = idx - 524288;
        int kg = i2 >> 11, col = i2 & 2047;
        int gate = col >> 9, ug = col & 511;
        int sl = ug >> 5, sloc = gate * 32 + (ug & 31);   // slice-local col: gate*32+unit
        int nt = sloc >> 4, c = sloc & 15, kt = kg >> 5, k = kg & 31;
        WhT[((size_t)sl << 16) + ((kt * 8 + nt) << 9) + c * 32 + k] = f2bf(Wh[i2]);
    } else if (idx < 524288 + 1048576 + 64) {
        bar[idx - (524288 + 1048576)] = 0;
    }
}

// ---------------- phase 1: Xg = bf16(x @ W_x + b), M=32768 N=2048 K=256 --------------------
__global__ __launch_bounds__(256) void lstm_xgemm(const float* __restrict__ x,
                                                  const short* __restrict__ WxT,
                                                  const float* __restrict__ b,
                                                  short* __restrict__ Xg) {
    __shared__ short Alds[128][40];           // 128x32 tile, +8 pad (bank spread), 16B-aligned rows
    int bx = blockIdx.x;
    // XCD swizzle: keep all 16 n-blocks of an m-panel on one XCD -> A panel read ~once from HBM
    int xcd = bx & 7, ix = bx >> 3;
    int mp = xcd * 32 + (ix >> 4), np = ix & 15;
    int m0 = mp * 128, n0 = np * 128;
    int tid = threadIdx.x;
    int w = tid >> 6, l = tid & 63;
    int wr = (w >> 1) * 64, wc = (w & 1) * 64;
    int lr = l & 15, lh = l >> 4;
    f32x4 acc[4][4] = {};
    int srow = tid >> 1, sk = (tid & 1) * 16;
    const short* bbase = WxT + lr * 32 + lh * 8;
    int ntg0 = (n0 + wc) >> 4;
    for (int ks = 0; ks < 8; ++ks) {
        int k0 = ks * 32;
        __syncthreads();
        // reg-stage A (f32 -> bf16 on the fly), coalesced 64B/lane
        const float* src = x + (size_t)(m0 + srow) * 256 + k0 + sk;
        float4 v0 = *(const float4*)(src + 0);
        float4 v1 = *(const float4*)(src + 4);
        float4 v2 = *(const float4*)(src + 8);
        float4 v3 = *(const float4*)(src + 12);
        bf16x8 p0, p1;
        p0[0]=f2bf(v0.x); p0[1]=f2bf(v0.y); p0[2]=f2bf(v0.z); p0[3]=f2bf(v0.w);
        p0[4]=f2bf(v1.x); p0[5]=f2bf(v1.y); p0[6]=f2bf(v1.z); p0[7]=f2bf(v1.w);
        p1[0]=f2bf(v2.x); p1[1]=f2bf(v2.y); p1[2]=f2bf(v2.z); p1[3]=f2bf(v2.w);
        p1[4]=f2bf(v3.x); p1[5]=f2bf(v3.y); p1[6]=f2bf(v3.z); p1[7]=f2bf(v3.w);
        *(bf16x8*)&Alds[srow][sk]     = p0;
        *(bf16x8*)&Alds[srow][sk + 8] = p1;
        __syncthreads();
        bf16x8 af[4], bf[4];
        #pragma unroll
        for (int mt = 0; mt < 4; ++mt)
            af[mt] = *(const bf16x8*)&Alds[wr + mt * 16 + lr][lh * 8];
        #pragma unroll
        for (int nt = 0; nt < 4; ++nt)
            bf[nt] = *(const bf16x8*)(bbase + ((size_t)((ks * 128 + ntg0 + nt)) << 9));
        #pragma unroll
        for (int mt = 0; mt < 4; ++mt)
            #pragma unroll
            for (int nt = 0; nt < 4; ++nt)
                acc[mt][nt] = __builtin_amdgcn_mfma_f32_16x16x32_bf16(af[mt], bf[nt], acc[mt][nt], 0, 0, 0);
    }
    // epilogue: D[row=(l>>4)*4+j][col=l&15] (m89-verified C/D layout)
    #pragma unroll
    for (int mt = 0; mt < 4; ++mt) {
        #pragma unroll
        for (int nt = 0; nt < 4; ++nt) {
            int col = n0 + wc + nt * 16 + lr;
            float bb = b[col];
            #pragma unroll
            for (int j = 0; j < 4; ++j) {
                int row = m0 + wr + mt * 16 + lh * 4 + j;
                Xg[(size_t)row * 2048 + col] = f2bf(acc[mt][nt][j] + bb);
            }
        }
    }
}

// ---------------- phase 2: persistent recurrence ------------------------------------------
// 64 WGs = 4 batch-groups (16 rows) x 16 hidden-slices (32 units = 128 gate cols).
// W_h slice streamed from L2 in frag layout; h exchanged via global bf16 double-buffer +
// per-group monotonic atomic barrier; c lives in one VGPR per thread.
__global__ __launch_bounds__(512) void lstm_rec(const short* __restrict__ Xg,
                                                const short* __restrict__ WhT,
                                                float* __restrict__ out,
                                                short* __restrict__ hbuf,
                                                int* __restrict__ bar) {
    __shared__ short hlds[16][520];   // h_t for this group's 16 rows, +8 pad
    __shared__ float glds[16][128];   // gate block (4 gates x 32 units)
    int bx = blockIdx.x;
    int g = bx >> 4, sl = bx & 15;
    int r0 = g * 16, u0 = sl * 32;
    int tid = threadIdx.x;
    int w = tid >> 6, l = tid & 63;
    int lr = l & 15, lh = l >> 4;
    int erow = tid >> 5, eunit = tid & 31;
    int* barg = bar + g * 16;                       // 64B apart
    const short* whb = WhT + ((size_t)sl << 16) + lr * 32 + lh * 8;
    {   // h0 = 0
        int cb = eunit * 16;
        #pragma unroll
        for (int j = 0; j < 16; ++j) hlds[erow][cb + j] = 0;
    }
    float creg = 0.f;
    __syncthreads();
    for (int t = 0; t < 512; ++t) {
        // issue Xg loads early; latency hides under the MFMA phase
        size_t xb = (size_t)t * (64 * 2048) + (size_t)(r0 + erow) * 2048 + u0 + eunit;
        float xi = bf2f(Xg[xb + 0]);
        float xf = bf2f(Xg[xb + 512]);
        float xg = bf2f(Xg[xb + 1024]);
        float xo = bf2f(Xg[xb + 1536]);
        // gates_h = h_t @ Wh_slice : wave w owns slice cols [16w,16w+16)
        f32x4 acc = {};
        #pragma unroll
        for (int kt = 0; kt < 16; ++kt) {
            bf16x8 af = *(const bf16x8*)&hlds[lr][kt * 32 + lh * 8];
            bf16x8 bf = *(const bf16x8*)(whb + ((kt * 8 + w) << 9));
            acc = __builtin_amdgcn_mfma_f32_16x16x32_bf16(af, bf, acc, 0, 0, 0);
        }
        #pragma unroll
        for (int j = 0; j < 4; ++j)
            glds[lh * 4 + j][w * 16 + lr] = acc[j];
        __syncthreads();
        // elementwise cell: thread -> (row=tid>>5, unit=tid&31)
        float gi = glds[erow][eunit +  0] + xi;
        float gf = glds[erow][eunit + 32] + xf;
        float gg = glds[erow][eunit + 64] + xg;
        float go = glds[erow][eunit + 96] + xo;
        gi = sigm(gi); gf = sigm(gf); go = sigm(go);
        creg = gf * creg + gi * tanh_(gg);
        float h = go * tanh_(creg);
        out[(size_t)t * (64 * 512) + (r0 + erow) * 512 + u0 + eunit] = h;
        if (t == 511) {
            out[(size_t)16777216 +         (r0 + erow) * 512 + u0 + eunit] = h;      // hT
            out[(size_t)16777216 + 32768 + (r0 + erow) * 512 + u0 + eunit] = creg;   // cT
        } else {
            // publish h_{t+1} (parity double-buffer), group barrier, reload full h
            hbuf[((t + 1) & 1) * 32768 + (r0 + erow) * 512 + u0 + eunit] = f2bf(h);
            __syncthreads();
            if (tid == 0) {
                __threadfence();  // device-scope release (L2 writeback for cross-XCD)
                __hip_atomic_fetch_add(barg, 1, __ATOMIC_RELEASE, __HIP_MEMORY_SCOPE_AGENT);
                int tgt = 16 * (t + 1);
                while (__hip_atomic_load(barg, __ATOMIC_RELAXED, __HIP_MEMORY_SCOPE_AGENT) < tgt)
                    __builtin_amdgcn_s_sleep(1);
                __threadfence();  // acquire: invalidate so hbuf reads are fresh
            }
            __syncthreads();
            {
                int cb = eunit * 16;
                const short* src2 = hbuf + ((t + 1) & 1) * 32768 + (r0 + erow) * 512 + cb;
                *(bf16x8*)&hlds[erow][cb + 0] = *(const bf16x8*)(src2 + 0);
                *(bf16x8*)&hlds[erow][cb + 8] = *(const bf16x8*)(src2 + 8);
            }
            __syncthreads();
        }
    }
}

extern "C" void kernel_launch(void* const* d_in, const int* in_sizes, int n_in,
                              void* d_out, int out_size, void* d_ws, size_t ws_size,
                              hipStream_t stream) {
    const float* x  = (const float*)d_in[0];
    const float* Wx = (const float*)d_in[1];
    const float* Wh = (const float*)d_in[2];
    const float* b  = (const float*)d_in[3];
    float* out = (float*)d_out;
    char* ws = (char*)d_ws;
    short* Xg   = (short*)(ws + XG_OFF);
    short* WxT  = (short*)(ws + WXT_OFF);
    short* WhT  = (short*)(ws + WHT_OFF);
    short* hbuf = (short*)(ws + HBUF_OFF);
    int*   bar  = (int*)(ws + BAR_OFF);

    lstm_prep <<<6145, 256, 0, stream>>>(Wx, Wh, WxT, WhT, bar);
    lstm_xgemm<<<4096, 256, 0, stream>>>(x, WxT, b, Xg);
    lstm_rec  <<<64,   512, 0, stream>>>(Xg, WhT, out, hbuf, bar);
}

// Round 3
// 2463.231 us; speedup vs baseline: 1.3803x; 1.3803x over previous
//
#include <hip/hip_runtime.h>
#include <hip/hip_bf16.h>

typedef __attribute__((ext_vector_type(8))) short bf16x8;
typedef __attribute__((ext_vector_type(4))) float f32x4;

// sizes: T=512 B=64 K=256 H=512 G=4H=2048
// ws layout (bytes):
static constexpr size_t XG_OFF   = 0;                        // bf16 Xg [32768][2048]  134217728 B
static constexpr size_t WXT_OFF  = 134217728;                // bf16 frag-tiled W_x     1048576 B
static constexpr size_t WHT_OFF  = WXT_OFF + 1048576;        // bf16 frag-tiled W_h     2097152 B
static constexpr size_t HBUF_OFF = WHT_OFF + 2097152;        // packed-bf16 h dbuf       131072 B
static constexpr size_t BAR_OFF  = HBUF_OFF + 131072;        // 4 barrier counters          256 B

static __device__ __forceinline__ short f2bf(float f) {
    union { float f; unsigned u; } v; v.f = f;
    return (short)((v.u + 0x7fff + ((v.u >> 16) & 1)) >> 16);   // RNE
}
static __device__ __forceinline__ float bf2f(short s) {
    union { unsigned u; float f; } v;
    v.u = ((unsigned)(unsigned short)s) << 16; return v.f;
}
static __device__ __forceinline__ float sigm(float x)  { return 1.f / (1.f + __expf(-x)); }
static __device__ __forceinline__ float tanh_(float x) { return 1.f - 2.f / (1.f + __expf(2.f * x)); }

// ---------------- prep: convert+transpose W_x/W_h into MFMA B-fragment tiling, zero barrier ----
__global__ __launch_bounds__(256) void lstm_prep(const float* __restrict__ Wx,
                                                 const float* __restrict__ Wh,
                                                 short* __restrict__ WxT,
                                                 short* __restrict__ WhT,
                                                 int* __restrict__ bar) {
    int idx = blockIdx.x * 256 + threadIdx.x;
    if (idx < 524288) {                       // W_x [256][2048]
        int kg = idx >> 11, col = idx & 2047;
        int kt = kg >> 5, k = kg & 31, nt = col >> 4, c = col & 15;
        WxT[(size_t)((kt * 128 + nt) << 9) + c * 32 + k] = f2bf(Wx[idx]);
    } else if (idx < 524288 + 1048576) {      // W_h [512][2048] -> 16 slices of 128 cols
        int i2 = idx - 524288;
        int kg = i2 >> 11, col = i2 & 2047;
        int gate = col >> 9, ug = col & 511;
        int sl = ug >> 5, sloc = gate * 32 + (ug & 31);   // slice-local col: gate*32+unit
        int nt = sloc >> 4, c = sloc & 15, kt = kg >> 5, k = kg & 31;
        WhT[((size_t)sl << 16) + ((kt * 8 + nt) << 9) + c * 32 + k] = f2bf(Wh[i2]);
    } else if (idx < 524288 + 1048576 + 64) {
        bar[idx - (524288 + 1048576)] = 0;
    }
}

// ---------------- phase 1: Xg = bf16(x @ W_x + b), M=32768 N=2048 K=256 --------------------
__global__ __launch_bounds__(256) void lstm_xgemm(const float* __restrict__ x,
                                                  const short* __restrict__ WxT,
                                                  const float* __restrict__ b,
                                                  short* __restrict__ Xg) {
    __shared__ short Alds[128][40];
    int bx = blockIdx.x;
    int xcd = bx & 7, ix = bx >> 3;
    int mp = xcd * 32 + (ix >> 4), np = ix & 15;
    int m0 = mp * 128, n0 = np * 128;
    int tid = threadIdx.x;
    int w = tid >> 6, l = tid & 63;
    int wr = (w >> 1) * 64, wc = (w & 1) * 64;
    int lr = l & 15, lh = l >> 4;
    f32x4 acc[4][4] = {};
    int srow = tid >> 1, sk = (tid & 1) * 16;
    const short* bbase = WxT + lr * 32 + lh * 8;
    int ntg0 = (n0 + wc) >> 4;
    for (int ks = 0; ks < 8; ++ks) {
        int k0 = ks * 32;
        __syncthreads();
        const float* src = x + (size_t)(m0 + srow) * 256 + k0 + sk;
        float4 v0 = *(const float4*)(src + 0);
        float4 v1 = *(const float4*)(src + 4);
        float4 v2 = *(const float4*)(src + 8);
        float4 v3 = *(const float4*)(src + 12);
        bf16x8 p0, p1;
        p0[0]=f2bf(v0.x); p0[1]=f2bf(v0.y); p0[2]=f2bf(v0.z); p0[3]=f2bf(v0.w);
        p0[4]=f2bf(v1.x); p0[5]=f2bf(v1.y); p0[6]=f2bf(v1.z); p0[7]=f2bf(v1.w);
        p1[0]=f2bf(v2.x); p1[1]=f2bf(v2.y); p1[2]=f2bf(v2.z); p1[3]=f2bf(v2.w);
        p1[4]=f2bf(v3.x); p1[5]=f2bf(v3.y); p1[6]=f2bf(v3.z); p1[7]=f2bf(v3.w);
        *(bf16x8*)&Alds[srow][sk]     = p0;
        *(bf16x8*)&Alds[srow][sk + 8] = p1;
        __syncthreads();
        bf16x8 af[4], bf[4];
        #pragma unroll
        for (int mt = 0; mt < 4; ++mt)
            af[mt] = *(const bf16x8*)&Alds[wr + mt * 16 + lr][lh * 8];
        #pragma unroll
        for (int nt = 0; nt < 4; ++nt)
            bf[nt] = *(const bf16x8*)(bbase + ((size_t)((ks * 128 + ntg0 + nt)) << 9));
        #pragma unroll
        for (int mt = 0; mt < 4; ++mt)
            #pragma unroll
            for (int nt = 0; nt < 4; ++nt)
                acc[mt][nt] = __builtin_amdgcn_mfma_f32_16x16x32_bf16(af[mt], bf[nt], acc[mt][nt], 0, 0, 0);
    }
    #pragma unroll
    for (int mt = 0; mt < 4; ++mt) {
        #pragma unroll
        for (int nt = 0; nt < 4; ++nt) {
            int col = n0 + wc + nt * 16 + lr;
            float bb = b[col];
            #pragma unroll
            for (int j = 0; j < 4; ++j) {
                int row = m0 + wr + mt * 16 + lh * 4 + j;
                Xg[(size_t)row * 2048 + col] = f2bf(acc[mt][nt][j] + bb);
            }
        }
    }
}

// ---------------- phase 2: persistent recurrence ------------------------------------------
// 64 WGs = 4 batch-groups (16 rows) x 16 hidden-slices (32 units = 128 gate cols).
// h exchanged via MALL using fine-grained relaxed agent-scope atomics (cache-bypassing;
// NO threadfence -> no bulk L2 writeback/invalidate, W_h stays L2-resident).
// hbuf: uint-packed 2xbf16, [parity][64 rows][256 pairs].
__global__ __launch_bounds__(512) void lstm_rec(const short* __restrict__ Xg,
                                                const short* __restrict__ WhT,
                                                float* __restrict__ out,
                                                unsigned* __restrict__ hbuf,
                                                int* __restrict__ bar) {
    __shared__ short hlds[16][520];   // h_t for this group's 16 rows (bf16)
    __shared__ float glds[16][132];   // gate block (4 gates x 32 units), padded stride
    int bx = blockIdx.x;
    int g = bx >> 4, sl = bx & 15;
    int r0 = g * 16, u0 = sl * 32;
    int tid = threadIdx.x;
    int w = tid >> 6, l = tid & 63;
    int lr = l & 15, lh = l >> 4;
    int erow = tid >> 5, eunit = tid & 31;
    int* barg = bar + g * 16;                       // 64B apart
    const short* whb = WhT + ((size_t)sl << 16) + lr * 32 + lh * 8;
    {   // h0 = 0
        int cb = eunit * 16;
        #pragma unroll
        for (int j = 0; j < 16; ++j) hlds[erow][cb + j] = 0;
    }
    float creg = 0.f;
    __syncthreads();
    for (int t = 0; t < 512; ++t) {
        // issue Xg loads early; latency hides under the MFMA phase
        size_t xb = (size_t)t * (64 * 2048) + (size_t)(r0 + erow) * 2048 + u0 + eunit;
        float xi = bf2f(Xg[xb + 0]);
        float xf = bf2f(Xg[xb + 512]);
        float xg = bf2f(Xg[xb + 1024]);
        float xo = bf2f(Xg[xb + 1536]);
        // gates_h = h_t @ Wh_slice : wave w owns slice cols [16w,16w+16)
        f32x4 acc = {};
        #pragma unroll
        for (int kt = 0; kt < 16; ++kt) {
            bf16x8 af = *(const bf16x8*)&hlds[lr][kt * 32 + lh * 8];
            bf16x8 bf = *(const bf16x8*)(whb + ((kt * 8 + w) << 9));
            acc = __builtin_amdgcn_mfma_f32_16x16x32_bf16(af, bf, acc, 0, 0, 0);
        }
        #pragma unroll
        for (int j = 0; j < 4; ++j)
            glds[lh * 4 + j][w * 16 + lr] = acc[j];
        __syncthreads();
        // elementwise cell: thread -> (row=tid>>5, unit=tid&31)
        float gi = glds[erow][eunit +  0] + xi;
        float gf = glds[erow][eunit + 32] + xf;
        float gg = glds[erow][eunit + 64] + xg;
        float go = glds[erow][eunit + 96] + xo;
        gi = sigm(gi); gf = sigm(gf); go = sigm(go);
        creg = gf * creg + gi * tanh_(gg);
        float h = go * tanh_(creg);
        out[(size_t)t * (64 * 512) + (r0 + erow) * 512 + u0 + eunit] = h;
        if (t == 511) {
            out[(size_t)16777216 +         (r0 + erow) * 512 + u0 + eunit] = h;      // hT
            out[(size_t)16777216 + 32768 + (r0 + erow) * 512 + u0 + eunit] = creg;   // cT
        } else {
            int par = (t + 1) & 1;
            // publish h_{t+1}: pack 2 bf16 per dword, fine-grained agent-scope store (bypasses L2)
            float hn = __shfl_xor(h, 1);
            if ((eunit & 1) == 0) {
                unsigned p = (unsigned)(unsigned short)f2bf(h)
                           | ((unsigned)(unsigned short)f2bf(hn) << 16);
                __hip_atomic_store(&hbuf[par * 16384 + (r0 + erow) * 256 + ((u0 + eunit) >> 1)],
                                   p, __ATOMIC_RELAXED, __HIP_MEMORY_SCOPE_AGENT);
            }
            // __syncthreads drains vmcnt(0) -> all h stores are at the coherence point
            __syncthreads();
            if (tid == 0) {
                __hip_atomic_fetch_add(barg, 1, __ATOMIC_RELAXED, __HIP_MEMORY_SCOPE_AGENT);
                int tgt = 16 * (t + 1);
                while (__hip_atomic_load(barg, __ATOMIC_RELAXED, __HIP_MEMORY_SCOPE_AGENT) < tgt)
                    __builtin_amdgcn_s_sleep(1);
            }
            __syncthreads();
            {   // reload full h (16 rows x 512) via cache-bypassing loads -> fresh MALL data
                const unsigned* src2 = hbuf + par * 16384 + (r0 + erow) * 256 + eunit * 8;
                unsigned pv[8];
                #pragma unroll
                for (int j = 0; j < 8; ++j)
                    pv[j] = __hip_atomic_load(&src2[j], __ATOMIC_RELAXED, __HIP_MEMORY_SCOPE_AGENT);
                int cb = eunit * 16;
                #pragma unroll
                for (int j = 0; j < 8; ++j)
                    *(unsigned*)&hlds[erow][cb + 2 * j] = pv[j];
            }
            __syncthreads();
        }
    }
}

extern "C" void kernel_launch(void* const* d_in, const int* in_sizes, int n_in,
                              void* d_out, int out_size, void* d_ws, size_t ws_size,
                              hipStream_t stream) {
    const float* x  = (const float*)d_in[0];
    const float* Wx = (const float*)d_in[1];
    const float* Wh = (const float*)d_in[2];
    const float* b  = (const float*)d_in[3];
    float* out = (float*)d_out;
    char* ws = (char*)d_ws;
    short* Xg      = (short*)(ws + XG_OFF);
    short* WxT     = (short*)(ws + WXT_OFF);
    short* WhT     = (short*)(ws + WHT_OFF);
    unsigned* hbuf = (unsigned*)(ws + HBUF_OFF);
    int*   bar     = (int*)(ws + BAR_OFF);

    lstm_prep <<<6145, 256, 0, stream>>>(Wx, Wh, WxT, WhT, bar);
    lstm_xgemm<<<4096, 256, 0, stream>>>(x, WxT, b, Xg);
    lstm_rec  <<<64,   512, 0, stream>>>(Xg, WhT, out, hbuf, bar);
}